// Round 14
// baseline (176.677 us; speedup 1.0000x reference)
//
#include <hip/hip_runtime.h>
#include <stdint.h>

typedef unsigned short u16;
typedef __bf16 bf16x8 __attribute__((ext_vector_type(8)));
typedef float f32x4 __attribute__((ext_vector_type(4)));

#define S_LEN 2048
#define NH    16
#define DM    1024
#define N3    3072
#define MROWS 4096   // B*S

// ---------- scalar bf16 helpers ----------
__device__ __forceinline__ float b2f(u16 u) {
  unsigned int v = ((unsigned int)u) << 16;
  return __builtin_bit_cast(float, v);
}
__device__ __forceinline__ u16 f2b(float f) {
  unsigned int v = __builtin_bit_cast(unsigned int, f);
  v += 0x7fffu + ((v >> 16) & 1u);   // RNE
  return (u16)(v >> 16);
}
__device__ __forceinline__ u16 f2b_trunc(float f) {
  return (u16)(__builtin_bit_cast(unsigned int, f) >> 16);
}
__device__ __forceinline__ bf16x8 ld8(const u16* p) { return *(const bf16x8*)p; }
__device__ __forceinline__ f32x4 mfma16(bf16x8 a, bf16x8 b, f32x4 c) {
  return __builtin_amdgcn_mfma_f32_16x16x32_bf16(a, b, c, 0, 0, 0);
}
__device__ __forceinline__ void glds16(const void* g, void* l) {
  __builtin_amdgcn_global_load_lds(
      (const __attribute__((address_space(1))) unsigned int*)g,
      (__attribute__((address_space(3))) unsigned int*)l, 16, 0, 0);
}
// bf16-vs-f32 word test: low-16 as bf16, exponent in [100,134]
__device__ __forceinline__ int bfish(unsigned int w) {
  unsigned int e = (w >> 7) & 0xffu;
  return (e >= 100u && e <= 134u) ? 1 : 0;
}
// wave-sum (64 lanes) -> lane0; then one atomicAdd per wave (kills LDS-atomic serialization)
__device__ __forceinline__ void wave_cnt_add(int* cnt, int s, int lane) {
  s += __shfl_down(s, 32);
  s += __shfl_down(s, 16);
  s += __shfl_down(s, 8);
  s += __shfl_down(s, 4);
  s += __shfl_down(s, 2);
  s += __shfl_down(s, 1);
  if (lane == 0) atomicAdd(cnt, s);
}

// ---------- fused prep: x->bf16 + cs table + both weight transposes + flag ----------
// blocks [0,2048): x conv | [2048,2560): cs table | [2560,3328): wqkv^T | [3328,3584): wout^T
__global__ __launch_bounds__(256) void prep_kernel(const void* __restrict__ x,
                                                   const void* __restrict__ wqkv,
                                                   const void* __restrict__ wout,
                                                   u16* __restrict__ xb,
                                                   u16* __restrict__ wqT,
                                                   u16* __restrict__ woT,
                                                   float* __restrict__ cs,
                                                   int* __restrict__ flag) {
  const int bx = blockIdx.x;
  const int t = threadIdx.x;
  if (bx < 2048) {                       // x -> bf16, self-detecting
    __shared__ int cnt;
    if (t == 0) cnt = 0;
    __syncthreads();
    size_t i = (size_t)bx * 256 + t;     // 524288 uint4 slots (safe both dtypes)
    const uint4* xv = (const uint4*)x;
    uint4 probe = xv[i];
    unsigned int wds[4]; *(uint4*)wds = probe;
    wave_cnt_add(&cnt, bfish(wds[0]) + bfish(wds[1]) + bfish(wds[2]) + bfish(wds[3]),
                 t & 63);
    __syncthreads();
    const int isbf = cnt > 512;
    if (t == 0) *flag = isbf;            // benign same-value race
    if (isbf) {
      ((uint4*)xb)[i] = probe;
    } else {
      // fp32 path, coalesced: 2x float4 loads (16B/lane contiguous) + uint2 stores
      const float4* xf4 = (const float4*)x;
      uint2* xb2 = (uint2*)xb;
      #pragma unroll
      for (int half = 0; half < 2; ++half) {
        const size_t idx = (size_t)bx * 512 + half * 256 + t;
        const float4 v = xf4[idx];
        u16 pk[4];
        pk[0] = f2b(v.x); pk[1] = f2b(v.y); pk[2] = f2b(v.z); pk[3] = f2b(v.w);
        xb2[idx] = *(const uint2*)pk;
      }
    }
    return;
  }
  if (bx < 2560) {                       // cs table: [2048 s][64 d] float2 (cos,sin)
    int i = (bx - 2048) * 256 + t;       // 131072 = 2048*64
    int s = i >> 6, d = i & 63;          // s-major -> coalesced float2 stores
    int f = d & 31;                      // concat(freqs,freqs): inv_freq index = d mod 32
    float invf = expf(-(float)(2 * f) * (1.0f / 64.0f) * logf(10000.0f));
    float th = (float)s * invf;
    float sv, cv;
    sincosf(th, &sv, &cv);
    cs[i * 2] = cv; cs[i * 2 + 1] = sv;  // i*2 == (s*64+d)*2
    return;
  }
  // weight transpose [R=1024][C] -> bf16 [C][1024], 64x64 tiles (V-transpose pattern)
  const int wq = bx < 3328;
  const int id = wq ? (bx - 2560) : (bx - 3328);
  const int ncx = wq ? 48 : 16;
  const void* in = wq ? wqkv : wout;
  u16* out = wq ? wqT : woT;
  const int C = wq ? 3072 : 1024;
  const int c0 = (id % ncx) * 64, r0 = (id / ncx) * 64;
  __shared__ int cnt;
  __shared__ u16 L[4096];                // [64 c][64 r], r-seg XOR swizzled
  if (t == 0) cnt = 0;
  __syncthreads();
  const unsigned int* wv = (const unsigned int*)in;
  size_t off = (((size_t)id) * 256 + t) & 262143;   // sample first 256K words (safe both)
  wave_cnt_add(&cnt, bfish(wv[off]), t & 63);
  __syncthreads();
  const int fl = cnt > 128;
  if (fl) {                              // bf16: uint4 loads, unpack into swizzled LDS
    #pragma unroll
    for (int it = 0; it < 2; ++it) {
      int c = it * 256 + t;
      int rl = c >> 3, cseg = c & 7;
      uint4 v = *(const uint4*)((const u16*)in + (size_t)(r0 + rl) * C + c0 + cseg * 8);
      u16 e[8]; *(uint4*)e = v;
      #pragma unroll
      for (int jj = 0; jj < 8; ++jj) {
        int cl = cseg * 8 + jj;
        L[cl * 64 + (rl ^ (cseg << 3))] = e[jj];
      }
    }
  } else {                               // fp32 fallback: scalar convert (already coalesced)
    const float* inf_ = (const float*)in;
    #pragma unroll
    for (int it = 0; it < 16; ++it) {
      int c = it * 256 + t;
      int rl = c >> 6, cl = c & 63;
      L[cl * 64 + (rl ^ ((cl >> 3) << 3))] = f2b(inf_[(size_t)(r0 + rl) * C + c0 + cl]);
    }
  }
  __syncthreads();
  #pragma unroll
  for (int it = 0; it < 2; ++it) {
    int c = it * 256 + t;
    int cl = c >> 3, rseg = c & 7;
    uint4 v = *(const uint4*)(L + cl * 64 + (((rseg ^ (cl >> 3)) & 7) << 3));
    *(uint4*)(out + (size_t)(c0 + cl) * 1024 + r0 + rseg * 8) = v;
  }
}

// ---------- QKV GEMM: 256x256 tile, BK=64, 8-wave 2-merged-phase counted-vmcnt ----------
// A: xb [4096][1024], Bt: wqT [3072][1024]
// Q,K -> [bh][2048][64] (Q pre-scaled by log2e/8); V -> Vt [bh][64][2048]
// r14: phases merged 4->2 per K-tile (barriers 8->4, lgkm drains 4->2). Invariants kept:
// B[kt] reg-loads complete before first barrier; B[kt+2] staged after it; A[kt+1] in
// phase A; vmcnt(4) leaves only B[kt+2] in flight. sched_barrier(0) REQUIRED (r5 A/B).

#define PHASE_PRE() do { \
  asm volatile("" ::: "memory"); \
  __builtin_amdgcn_s_barrier(); \
  asm volatile("s_waitcnt lgkmcnt(0)" ::: "memory"); \
  __builtin_amdgcn_sched_barrier(0); \
  __builtin_amdgcn_s_setprio(1); \
} while (0)

#define PHASE_POST() do { \
  __builtin_amdgcn_s_setprio(0); \
  asm volatile("" ::: "memory"); \
  __builtin_amdgcn_s_barrier(); \
} while (0)

#define LOADA2(P) \
  _Pragma("unroll") \
  for (int ii = 0; ii < 4; ++ii) { \
    const int row = wr * 128 + ((P) * 4 + ii) * 16 + ln; \
    _Pragma("unroll") \
    for (int kk = 0; kk < 2; ++kk) \
      a[ii][kk] = ld8(Ap + row * 64 + (((kk * 4 + quad) ^ (row & 7)) << 3)); \
  }

#define MFMAQ2(P) \
  _Pragma("unroll") \
  for (int ii = 0; ii < 4; ++ii) { \
    _Pragma("unroll") \
    for (int j = 0; j < 4; ++j) { \
      acc[(P) * 4 + ii][j] = mfma16(a[ii][0], b[j][0], acc[(P) * 4 + ii][j]); \
      acc[(P) * 4 + ii][j] = mfma16(a[ii][1], b[j][1], acc[(P) * 4 + ii][j]); \
    } \
  }

__global__ __launch_bounds__(512, 2) void gemm_qkv(const u16* __restrict__ A,
                                                   const u16* __restrict__ Bt,
                                                   u16* __restrict__ Qo,
                                                   u16* __restrict__ Ko,
                                                   u16* __restrict__ Vt,
                                                   const float* __restrict__ cs) {
  __shared__ u16 smem[2][32768];        // per buf: A[256][64] | B[256][64] = 64 KB; 128 KB total
  const int t = threadIdx.x;
  const int lane = t & 63, wave = t >> 6;
  const int ln = lane & 15, quad = lane >> 4;
  const int wr = wave >> 2, wc = wave & 3;        // 2M x 4N waves; per-wave C = 128x64
  const int m0 = blockIdx.x * 256, n0 = blockIdx.y * 256;
  const u16* gA0 = A + (size_t)m0 * 1024;
  const u16* gA1 = A + (size_t)(m0 + 128) * 1024;
  const u16* gB0 = Bt + (size_t)n0 * 1024;
  const u16* gB1 = Bt + (size_t)(n0 + 128) * 1024;
  f32x4 acc[8][4] = {};

  // stage one 128x64 half-tile: 1024 chunks of 16B, 2 glds/wave-lane.
  // LDS linear in chunk c; source chunk pre-inverse-swizzled (rule #21 pattern).
  auto stage_half = [&](u16* lds, const u16* g, int k0) {
    #pragma unroll
    for (int it = 0; it < 2; ++it) {
      const int c = it * 512 + t;
      const int row = c >> 3, sg = (c & 7) ^ (row & 7);
      glds16(g + (size_t)row * 1024 + k0 + sg * 8, (char*)lds + c * 16);
    }
  };

  // prologue: all of K-tile 0 + B halves of K-tile 1 (A[1] staged during kt=0)
  stage_half(&smem[0][0],     gA0, 0);
  stage_half(&smem[0][8192],  gA1, 0);
  stage_half(&smem[0][16384], gB0, 0);
  stage_half(&smem[0][24576], gB1, 0);
  stage_half(&smem[1][16384], gB0, 64);
  stage_half(&smem[1][24576], gB1, 64);
  asm volatile("s_waitcnt vmcnt(4)" ::: "memory");   // K-tile 0 landed; B[1] may fly
  __builtin_amdgcn_s_barrier();

  for (int kt = 0; kt < 16; ++kt) {
    const int p = kt & 1;
    u16* Ap = &smem[p][0];
    u16* Bp = &smem[p][16384];
    u16* Aq = &smem[p ^ 1][0];
    const int kA = (kt + 1) * 64, kB = (kt + 2) * 64;
    bf16x8 b[4][2], a[4][2];
    // ---- phase A: full B frags + a rows 0..63 | stage A0,A1[kt+1] -> q ----
    #pragma unroll
    for (int j = 0; j < 4; ++j) {
      const int row = wc * 64 + j * 16 + ln;
      #pragma unroll
      for (int kk = 0; kk < 2; ++kk)
        b[j][kk] = ld8(Bp + row * 64 + (((kk * 4 + quad) ^ (row & 7)) << 3));
    }
    LOADA2(0);
    if (kt < 15) { stage_half(Aq, gA0, kA); stage_half(Aq + 8192, gA1, kA); }
    PHASE_PRE(); MFMAQ2(0); PHASE_POST();
    // ---- phase B: a rows 64..127 | stage B0,B1[kt+2] -> p (B[kt] consumed) ----
    LOADA2(1);
    if (kt < 14) { stage_half(Bp, gB0, kB); stage_half(Bp + 8192, gB1, kB); }
    PHASE_PRE(); MFMAQ2(1);
    __builtin_amdgcn_s_setprio(0);
    if (kt < 14) { asm volatile("s_waitcnt vmcnt(4)" ::: "memory"); }
    else         { asm volatile("s_waitcnt vmcnt(0)" ::: "memory"); }
    asm volatile("" ::: "memory");
    __builtin_amdgcn_s_barrier();
  }

  // ---- epilogue: LDS re-tile -> coalesced stores ----
  // smem is free (final vmcnt(0)+barrier). Tl = 128 KB = full 256x256 bf16 C-tile.
  u16* Tl = &smem[0][0];
  const int which = n0 >> 10;                    // 0=Q 1=K 2=V, block-uniform
  const int b_ = m0 >> 11;                       // tile never crosses batch (2048%256==0)
  const int s0 = m0 & 2047;
  const int h0 = (n0 & 1023) >> 6;               // first of 4 heads in this block

  if (which < 2) {
    // --- E1: RoPE in regs, stage to row-major T[s][c], chunk-rotate swizzle ---
    // byte = sl*512 + (((c>>3) + 4*(sl&7)) & 31)*16 + (c&7)*2
    const float qs = which ? 1.0f : 0.18033688011112042f;  // log2(e)/8 on Q
    const float2* cs2 = (const float2*)cs;       // [s][64 d] (cos,sin)
    #pragma unroll
    for (int i = 0; i < 8; ++i) {
      const int slb = wr * 128 + i * 16 + quad * 4;
      #pragma unroll
      for (int j = 0; j < 4; ++j) {
        const int c = wc * 64 + j * 16 + ln;     // 0..255 block-local col
        const int d = c & 63;
        const float sgn = (d & 1) ? 1.0f : -1.0f;
        #pragma unroll
        for (int r = 0; r < 4; ++r) {
          const int sl = slb + r;
          const float v = acc[i][j][r];
          const float pp = __shfl_xor(v, 1);     // rotate-half partner (d^1)
          const float2 cv = cs2[(size_t)(s0 + sl) * 64 + d];
          const float val = (v * cv.x + sgn * pp * cv.y) * qs;
          *(u16*)((char*)Tl + sl * 512 + ((((c >> 3) + 4 * (sl & 7)) & 31) << 4)
                  + ((c & 7) << 1)) = f2b(val);
        }
      }
    }
    __syncthreads();
    // --- E2: wide stores; per instr 8 rows x 128 B contiguous ---
    u16* dst = which ? Ko : Qo;
    #pragma unroll
    for (int it = 0; it < 16; ++it) {
      const int g = it * 512 + t;                // [h(2)][sl(8)][c3(3)]
      const int c3 = g & 7, sl = (g >> 3) & 255, h = g >> 11;
      const int ch = h * 8 + c3;                 // chunk index within row (c>>3)
      const uint4 vv = *(const uint4*)((const char*)Tl + sl * 512
                        + (((ch + 4 * (sl & 7)) & 31) << 4));
      *(uint4*)(dst + ((size_t)(b_ * NH + h0 + h) * S_LEN + s0 + sl) * 64 + c3 * 8) = vv;
    }
  } else {
    // --- E1: stage to col-major T2[c][s]; r=0..3 are s-contiguous -> uint2 writes ---
    // byte = c*512 + (((s>>3) + c) & 31)*16 + (s&7)*2   (s&7 in {0,4} -> aligned uint2)
    #pragma unroll
    for (int i = 0; i < 8; ++i) {
      const int slb = wr * 128 + i * 16 + quad * 4;
      #pragma unroll
      for (int j = 0; j < 4; ++j) {
        const int c = wc * 64 + j * 16 + ln;
        u16 pk[4];
        #pragma unroll
        for (int r = 0; r < 4; ++r) pk[r] = f2b(acc[i][j][r]);
        *(uint2*)((char*)Tl + c * 512 + ((((slb >> 3) + c) & 31) << 4)
                  + ((slb & 7) << 1)) = *(const uint2*)pk;
      }
    }
    __syncthreads();
    // --- E2: per instr 2 rows x 512 B contiguous into Vt [bh][64][2048] ---
    #pragma unroll
    for (int it = 0; it < 16; ++it) {
      const int g = it * 512 + t;                // [c(8)][sc(5)]
      const int sc = g & 31, cd = g >> 5;        // cd = block-local col 0..255
      const int h = cd >> 6, d = cd & 63;
      const uint4 vv = *(const uint4*)((const char*)Tl + cd * 512
                        + (((sc + cd) & 31) << 4));
      *(uint4*)(&Vt[((size_t)((b_ * NH + h0 + h) * 64 + d)) * S_LEN + s0 + sc * 8]) = vv;
    }
  }
}

#undef PHASE_PRE
#undef PHASE_POST
#undef LOADA2
#undef MFMAQ2

// ---------- flash attention, S^T/O^T formulation, QBLK=64 (r7-verbatim, validated) ----------
// Q,K: [bh][2048][64] (Q pre-scaled), Vt: [bh][64][2048]; Ao: [4096][1024] bf16
// r11 lesson: staging is the latency-hiding structure, not a BW filter — keep it.
__global__ __launch_bounds__(256) void attn_kernel(const u16* __restrict__ Qb,
                                                   const u16* __restrict__ Kb,
                                                   const u16* __restrict__ Vt,
                                                   u16* __restrict__ Ao) {
  __shared__ u16 smem[20480];          // Kl 2x4096 | Vl 2x4096 | Pl 4x1024 = 40960 B
  u16* Kl = smem;
  u16* Vl = smem + 8192;
  u16* Pl = smem + 16384;
  const int t = threadIdx.x;
  const int lane = t & 63, w = t >> 6;
  const int ln = lane & 15, quad = lane >> 4;
  // block decode: xcd-local bh (L2 reuse), per-CU-balanced qt
  const int i = blockIdx.x;
  const int xcd = i & 7;
  const int j = i >> 3;                  // 0..127
  const int bh = (xcd << 2) | (j & 3);   // 4 bh per XCD -> K/V L2-resident
  const int q5 = j >> 2;                 // 0..31
  const int g = q5 & 7, s5 = q5 >> 3;
  const int qt = (s5 & 1) ? (31 - ((s5 >> 1) << 3) - g) : (((s5 >> 1) << 3) + g);
  const int q0 = qt * 64;
  const int b = bh >> 4, h = bh & 15;
  const u16* Qbh = Qb + (size_t)bh * (S_LEN * 64);
  const u16* Kbh = Kb + (size_t)bh * (S_LEN * 64);
  const u16* Vtbh = Vt + (size_t)bh * (64 * S_LEN);
  u16* Plw = Pl + w * 1024;              // per-wave [16 q][64 t], 8-chunk XOR swizzled
  u16* AoBase = Ao + (size_t)b * S_LEN * DM + h * 64;

  auto stage = [&](int kt, int bufi) {
    u16* kd = Kl + bufi * 4096;
    u16* vd = Vl + bufi * 4096;
    const u16* kg = Kbh + (size_t)kt * 64 * 64;
    const u16* vg = Vtbh + (size_t)kt * 64;
    #pragma unroll
    for (int it = 0; it < 2; ++it) {
      int c = it * 256 + t;
      int row = c >> 3, sg = (c & 7) ^ (row & 7);
      glds16((const char*)kg + ((size_t)row * 64 + sg * 8) * 2,   (char*)kd + c * 16);
      glds16((const char*)vg + ((size_t)row * 2048 + sg * 8) * 2, (char*)vd + c * 16);
    }
  };

  // Q as B-fragment: n = this wave's 16 q rows
  bf16x8 bq[2];
  #pragma unroll
  for (int kk = 0; kk < 2; ++kk)
    bq[kk] = ld8(Qbh + (size_t)(q0 + w * 16 + ln) * 64 + kk * 32 + quad * 8);

  f32x4 o[4] = {};                       // O^T tiles: m=d (4 tiles), n=q
  float l = 0.f;                         // per-lane partial sum for q=ln over this quad's t

  stage(0, 0);
  __syncthreads();

  for (int kt = 0; kt <= qt; ++kt) {
    const int bufi = kt & 1;
    if (kt < qt) stage(kt + 1, bufi ^ 1);   // prefetch overlaps compute
    const u16* Kb_ = Kl + bufi * 4096;
    const u16* Vb_ = Vl + bufi * 4096;

    // S^T = K Q^T: A=K (m=t), B=Q (n=q)
    f32x4 st[4] = {};
    #pragma unroll
    for (int kk = 0; kk < 2; ++kk)
      #pragma unroll
      for (int ct = 0; ct < 4; ++ct) {
        bf16x8 ak = ld8(Kb_ + (ct * 16 + ln) * 64 + (((kk * 4 + quad) ^ (ln & 7)) << 3));
        st[ct] = mfma16(ak, bq[kk], st[ct]);
      }

    // exp2 + causal mask + l accumulate + P store (b64, swizzled)
    const bool diag = (kt == qt);
    #pragma unroll
    for (int ct = 0; ct < 4; ++ct) {
      u16 pk[4];
      #pragma unroll
      for (int r = 0; r < 4; ++r) {
        float p;
        if (diag && (ct * 16 + quad * 4 + r) > (w * 16 + ln)) p = 0.f;
        else p = __builtin_amdgcn_exp2f(st[ct][r]);
        l += p;
        pk[r] = f2b_trunc(p);
      }
      *(uint2*)(Plw + ln * 64 + ((((ct * 2) + (quad >> 1)) ^ (ln & 7)) << 3)
                + ((quad & 1) << 2)) = *(const uint2*)pk;
    }

    // O^T += Vt P^T: A=Vt (m=d), B=P (n=q)
    #pragma unroll
    for (int k4 = 0; k4 < 2; ++k4) {
      bf16x8 bp = ld8(Plw + ln * 64 + (((k4 * 4 + quad) ^ (ln & 7)) << 3));
      #pragma unroll
      for (int dt = 0; dt < 4; ++dt) {
        bf16x8 av = ld8(Vb_ + (dt * 16 + ln) * 64 + (((k4 * 4 + quad) ^ (ln & 7)) << 3));
        o[dt] = mfma16(av, bp, o[dt]);
      }
    }
    __syncthreads();                         // buf consumed; prefetch drained
  }

  // l: sum across the 4 quads holding q=ln
  l += __shfl_xor(l, 16);
  l += __shfl_xor(l, 32);
  const float inv = 1.f / l;
  const size_t qrow = (size_t)(q0 + w * 16 + ln) * DM;
  #pragma unroll
  for (int dt = 0; dt < 4; ++dt) {
    u16 pk[4];
    #pragma unroll
    for (int r = 0; r < 4; ++r) pk[r] = f2b(o[dt][r] * inv);
    *(uint2*)(AoBase + qrow + dt * 16 + quad * 4) = *(const uint2*)pk;
  }
}

// ---------- out-projection GEMM, TM x 128, BK=64, XOR-swizzled staging (r8, -3.3us) ----------
template <int TM>
__global__ __launch_bounds__(256) void gemm_out_t(const u16* __restrict__ A,
                                                  const u16* __restrict__ Bt,
                                                  void* __restrict__ Out,
                                                  const int* __restrict__ flag) {
  constexpr int MI = TM / 32;
  __shared__ u16 smem[(TM + 128) * 64];   // Al[TM][64] | Bl[128][64]
  u16* Al = smem;
  u16* Bl = smem + TM * 64;
  const int t = threadIdx.x;
  const int lane = t & 63, wave = t >> 6;
  const int ln = lane & 15, quad = lane >> 4;
  const int wr = wave >> 1, wc = wave & 1;
  const int m0 = blockIdx.x * TM, n0 = blockIdx.y * 128;
  const char* Ab = (const char*)A;
  const char* Bb = (const char*)Bt;
  f32x4 acc[MI][4] = {};

  for (int k0 = 0; k0 < 1024; k0 += 64) {
    __syncthreads();
    #pragma unroll
    for (int it = 0; it < TM / 32; ++it) {        // A: TM*8 chunks
      const int c = it * 256 + t;
      const int row = c >> 3, sg = (c & 7) ^ (row & 7);
      glds16(Ab + ((size_t)(m0 + row) * 1024 + k0 + sg * 8) * 2, (char*)Al + c * 16);
    }
    #pragma unroll
    for (int it = 0; it < 4; ++it) {              // B: 1024 chunks
      const int c = it * 256 + t;
      const int row = c >> 3, sg = (c & 7) ^ (row & 7);
      glds16(Bb + ((size_t)(n0 + row) * 1024 + k0 + sg * 8) * 2, (char*)Bl + c * 16);
    }
    __syncthreads();
    bf16x8 a[MI][2], b[4][2];
    #pragma unroll
    for (int i = 0; i < MI; ++i) {
      const int row = wr * (TM / 2) + i * 16 + ln;
      #pragma unroll
      for (int kk = 0; kk < 2; ++kk)
        a[i][kk] = ld8(Al + row * 64 + (((kk * 4 + quad) ^ (row & 7)) << 3));
    }
    #pragma unroll
    for (int j = 0; j < 4; ++j) {
      const int row = wc * 64 + j * 16 + ln;
      #pragma unroll
      for (int kk = 0; kk < 2; ++kk)
        b[j][kk] = ld8(Bl + row * 64 + (((kk * 4 + quad) ^ (row & 7)) << 3));
    }
    #pragma unroll
    for (int i = 0; i < MI; ++i)
      #pragma unroll
      for (int j = 0; j < 4; ++j) {
        acc[i][j] = mfma16(a[i][0], b[j][0], acc[i][j]);
        acc[i][j] = mfma16(a[i][1], b[j][1], acc[i][j]);
      }
  }

  const int fl = *flag;
  #pragma unroll
  for (int i = 0; i < MI; ++i)
    #pragma unroll
    for (int j = 0; j < 4; ++j)
      #pragma unroll
      for (int r = 0; r < 4; ++r) {
        int m = m0 + wr * (TM / 2) + i * 16 + quad * 4 + r;
        int c = n0 + wc * 64 + j * 16 + ln;
        float v = acc[i][j][r];
        if (fl) ((u16*)Out)[(size_t)m * DM + c] = f2b(v);
        else    ((float*)Out)[(size_t)m * DM + c] = v;
      }
}

// ---------- launch ----------
extern "C" void kernel_launch(void* const* d_in, const int* in_sizes, int n_in,
                              void* d_out, int out_size, void* d_ws, size_t ws_size,
                              hipStream_t stream) {
  (void)in_sizes; (void)n_in; (void)out_size; (void)ws_size;
  const void* x    = d_in[0];
  const void* wqkv = d_in[2];
  const void* wout = d_in[3];
  char* ws = (char*)d_ws;
  u16*  xb   = (u16*)(ws + 0);            // 8 MB [4096][1024]; Ao aliases after gemm_qkv
  u16*  Ao   = xb;
  u16*  wqT  = (u16*)(ws + 8388608);      // 6 MB [3072][1024]
  u16*  woT  = (u16*)(ws + 14680064);     // 2 MB [1024][1024]
  u16*  Qb   = (u16*)(ws + 16777216);     // 8 MB [32][2048][64]
  u16*  Kb   = (u16*)(ws + 25165824);     // 8 MB
  u16*  Vt   = (u16*)(ws + 33554432);     // 8 MB [32][64][2048]
  float* cs  = (float*)(ws + 41943040);   // 1 MB [2048 s][64 d] float2 (cos,sin)
  int*  flag = (int*)(ws + 42991616);

  prep_kernel<<<3584, 256, 0, stream>>>(x, wqkv, wout, xb, wqT, woT, cs, flag);
  gemm_qkv<<<dim3(16, 12), 512, 0, stream>>>(xb, wqT, Qb, Kb, Vt, cs);
  attn_kernel<<<1024, 256, 0, stream>>>(Qb, Kb, Vt, Ao);
  gemm_out_t<64><<<dim3(64, 8), 256, 0, stream>>>(Ao, woT, d_out, flag);
}

// Round 16
// 174.425 us; speedup vs baseline: 1.0129x; 1.0129x over previous
//
#include <hip/hip_runtime.h>
#include <stdint.h>

typedef unsigned short u16;
typedef __bf16 bf16x8 __attribute__((ext_vector_type(8)));
typedef float f32x4 __attribute__((ext_vector_type(4)));

#define S_LEN 2048
#define NH    16
#define DM    1024
#define N3    3072
#define MROWS 4096   // B*S

// ---------- scalar bf16 helpers ----------
__device__ __forceinline__ float b2f(u16 u) {
  unsigned int v = ((unsigned int)u) << 16;
  return __builtin_bit_cast(float, v);
}
__device__ __forceinline__ u16 f2b(float f) {
  unsigned int v = __builtin_bit_cast(unsigned int, f);
  v += 0x7fffu + ((v >> 16) & 1u);   // RNE
  return (u16)(v >> 16);
}
__device__ __forceinline__ u16 f2b_trunc(float f) {
  return (u16)(__builtin_bit_cast(unsigned int, f) >> 16);
}
__device__ __forceinline__ bf16x8 ld8(const u16* p) { return *(const bf16x8*)p; }
__device__ __forceinline__ f32x4 mfma16(bf16x8 a, bf16x8 b, f32x4 c) {
  return __builtin_amdgcn_mfma_f32_16x16x32_bf16(a, b, c, 0, 0, 0);
}
__device__ __forceinline__ void glds16(const void* g, void* l) {
  __builtin_amdgcn_global_load_lds(
      (const __attribute__((address_space(1))) unsigned int*)g,
      (__attribute__((address_space(3))) unsigned int*)l, 16, 0, 0);
}
// bf16-vs-f32 word test: low-16 as bf16, exponent in [100,134]
__device__ __forceinline__ int bfish(unsigned int w) {
  unsigned int e = (w >> 7) & 0xffu;
  return (e >= 100u && e <= 134u) ? 1 : 0;
}
// wave-sum (64 lanes) -> lane0; then one atomicAdd per wave
__device__ __forceinline__ void wave_cnt_add(int* cnt, int s, int lane) {
  s += __shfl_down(s, 32);
  s += __shfl_down(s, 16);
  s += __shfl_down(s, 8);
  s += __shfl_down(s, 4);
  s += __shfl_down(s, 2);
  s += __shfl_down(s, 1);
  if (lane == 0) atomicAdd(cnt, s);
}

// ---------- fused prep: x->bf16 + cs table + both weight transposes + flag ----------
// blocks [0,2048): x conv | [2048,2560): cs table | [2560,3328): wqkv^T | [3328,3584): wout^T
__global__ __launch_bounds__(256) void prep_kernel(const void* __restrict__ x,
                                                   const void* __restrict__ wqkv,
                                                   const void* __restrict__ wout,
                                                   u16* __restrict__ xb,
                                                   u16* __restrict__ wqT,
                                                   u16* __restrict__ woT,
                                                   float* __restrict__ cs,
                                                   int* __restrict__ flag) {
  const int bx = blockIdx.x;
  const int t = threadIdx.x;
  if (bx < 2048) {                       // x -> bf16, self-detecting
    __shared__ int cnt;
    if (t == 0) cnt = 0;
    __syncthreads();
    size_t i = (size_t)bx * 256 + t;     // 524288 uint4 slots (safe both dtypes)
    const uint4* xv = (const uint4*)x;
    uint4 probe = xv[i];
    unsigned int wds[4]; *(uint4*)wds = probe;
    wave_cnt_add(&cnt, bfish(wds[0]) + bfish(wds[1]) + bfish(wds[2]) + bfish(wds[3]),
                 t & 63);
    __syncthreads();
    const int isbf = cnt > 512;
    if (t == 0) *flag = isbf;            // benign same-value race
    if (isbf) {
      ((uint4*)xb)[i] = probe;
    } else {
      // fp32 path, coalesced: 2x float4 loads (16B/lane contiguous) + uint2 stores
      const float4* xf4 = (const float4*)x;
      uint2* xb2 = (uint2*)xb;
      #pragma unroll
      for (int half = 0; half < 2; ++half) {
        const size_t idx = (size_t)bx * 512 + half * 256 + t;
        const float4 v = xf4[idx];
        u16 pk[4];
        pk[0] = f2b(v.x); pk[1] = f2b(v.y); pk[2] = f2b(v.z); pk[3] = f2b(v.w);
        xb2[idx] = *(const uint2*)pk;
      }
    }
    return;
  }
  if (bx < 2560) {                       // cs table: [2048 s][64 d] float2 (cos,sin)
    int i = (bx - 2048) * 256 + t;       // 131072 = 2048*64
    int s = i >> 6, d = i & 63;          // s-major -> coalesced float2 stores
    int f = d & 31;                      // concat(freqs,freqs): inv_freq index = d mod 32
    float invf = expf(-(float)(2 * f) * (1.0f / 64.0f) * logf(10000.0f));
    float th = (float)s * invf;
    float sv, cv;
    sincosf(th, &sv, &cv);
    cs[i * 2] = cv; cs[i * 2 + 1] = sv;  // i*2 == (s*64+d)*2
    return;
  }
  // weight transpose [R=1024][C] -> bf16 [C][1024], 64x64 tiles (V-transpose pattern)
  const int wq = bx < 3328;
  const int id = wq ? (bx - 2560) : (bx - 3328);
  const int ncx = wq ? 48 : 16;
  const void* in = wq ? wqkv : wout;
  u16* out = wq ? wqT : woT;
  const int C = wq ? 3072 : 1024;
  const int c0 = (id % ncx) * 64, r0 = (id / ncx) * 64;
  __shared__ int cnt;
  __shared__ u16 L[4096];                // [64 c][64 r], r-seg XOR swizzled
  if (t == 0) cnt = 0;
  __syncthreads();
  const unsigned int* wv = (const unsigned int*)in;
  size_t off = (((size_t)id) * 256 + t) & 262143;   // sample first 256K words (safe both)
  wave_cnt_add(&cnt, bfish(wv[off]), t & 63);
  __syncthreads();
  const int fl = cnt > 128;
  if (fl) {                              // bf16: uint4 loads, unpack into swizzled LDS
    #pragma unroll
    for (int it = 0; it < 2; ++it) {
      int c = it * 256 + t;
      int rl = c >> 3, cseg = c & 7;
      uint4 v = *(const uint4*)((const u16*)in + (size_t)(r0 + rl) * C + c0 + cseg * 8);
      u16 e[8]; *(uint4*)e = v;
      #pragma unroll
      for (int jj = 0; jj < 8; ++jj) {
        int cl = cseg * 8 + jj;
        L[cl * 64 + (rl ^ (cseg << 3))] = e[jj];
      }
    }
  } else {                               // fp32 fallback: scalar convert (already coalesced)
    const float* inf_ = (const float*)in;
    #pragma unroll
    for (int it = 0; it < 16; ++it) {
      int c = it * 256 + t;
      int rl = c >> 6, cl = c & 63;
      L[cl * 64 + (rl ^ ((cl >> 3) << 3))] = f2b(inf_[(size_t)(r0 + rl) * C + c0 + cl]);
    }
  }
  __syncthreads();
  #pragma unroll
  for (int it = 0; it < 2; ++it) {
    int c = it * 256 + t;
    int cl = c >> 3, rseg = c & 7;
    uint4 v = *(const uint4*)(L + cl * 64 + (((rseg ^ (cl >> 3)) & 7) << 3));
    *(uint4*)(out + (size_t)(c0 + cl) * 1024 + r0 + rseg * 8) = v;
  }
}

// ---------- QKV GEMM: 128x128 tile, BK=64, 4-wave merged-2-phase counted-vmcnt ----------
// A: xb [4096][1024], Bt: wqT [3072][1024]
// Q,K -> [bh][2048][64] (Q pre-scaled by log2e/8); V -> Vt [bh][64][2048]
// r16: r15 + staging-undercount FIX (stage_t it<4: 1024 chunks = full 128x64 tile;
// r15's it<2 left rows 64..127 unstaged -> NaN). vmcnt rescaled 2->4 (4 glds/stage).
// 64KB LDS => 2 blocks/CU co-resident; grid 768 = full CU coverage.
// sched_barrier(0) after lgkm REQUIRED (r5 A/B); setprio around MFMA.

#define PHASE_PRE() do { \
  asm volatile("" ::: "memory"); \
  __builtin_amdgcn_s_barrier(); \
  asm volatile("s_waitcnt lgkmcnt(0)" ::: "memory"); \
  __builtin_amdgcn_sched_barrier(0); \
  __builtin_amdgcn_s_setprio(1); \
} while (0)

#define PHASE_POST() do { \
  __builtin_amdgcn_s_setprio(0); \
  asm volatile("" ::: "memory"); \
  __builtin_amdgcn_s_barrier(); \
} while (0)

#define LOADA(P) \
  _Pragma("unroll") \
  for (int ii = 0; ii < 2; ++ii) { \
    const int row = wr * 64 + ((P) * 2 + ii) * 16 + ln; \
    _Pragma("unroll") \
    for (int kk = 0; kk < 2; ++kk) \
      a[ii][kk] = ld8(Ap + row * 64 + (((kk * 4 + quad) ^ (row & 7)) << 3)); \
  }

#define MFMAQ(P) \
  _Pragma("unroll") \
  for (int ii = 0; ii < 2; ++ii) { \
    _Pragma("unroll") \
    for (int j = 0; j < 4; ++j) { \
      acc[(P) * 2 + ii][j] = mfma16(a[ii][0], b[j][0], acc[(P) * 2 + ii][j]); \
      acc[(P) * 2 + ii][j] = mfma16(a[ii][1], b[j][1], acc[(P) * 2 + ii][j]); \
    } \
  }

__global__ __launch_bounds__(256) void gemm_qkv(const u16* __restrict__ A,
                                                const u16* __restrict__ Bt,
                                                u16* __restrict__ Qo,
                                                u16* __restrict__ Ko,
                                                u16* __restrict__ Vt,
                                                const float* __restrict__ cs) {
  __shared__ u16 smem[2][16384];        // per buf: A[128][64] | B[128][64] = 32 KB; 64 KB total
  const int t = threadIdx.x;
  const int lane = t & 63, wave = t >> 6;
  const int ln = lane & 15, quad = lane >> 4;
  const int wr = wave >> 1, wc = wave & 1;        // 2M x 2N waves; per-wave C = 64x64
  const int m0 = blockIdx.x * 128, n0 = blockIdx.y * 128;
  const u16* gA = A + (size_t)m0 * 1024;
  const u16* gB = Bt + (size_t)n0 * 1024;
  f32x4 acc[4][4] = {};

  // stage one 128x64 tile: 1024 chunks of 16B, 4 glds/thread; inverse-swz source.
  auto stage_t = [&](u16* lds, const u16* g, int k0) {
    #pragma unroll
    for (int it = 0; it < 4; ++it) {
      const int c = it * 256 + t;
      const int row = c >> 3, sg = (c & 7) ^ (row & 7);
      glds16(g + (size_t)row * 1024 + k0 + sg * 8, (char*)lds + c * 16);
    }
  };

  // prologue: A[0],B[0] -> buf0; B[1] -> buf1 (A[1] staged during kt=0)
  stage_t(&smem[0][0],    gA, 0);
  stage_t(&smem[0][8192], gB, 0);
  stage_t(&smem[1][8192], gB, 64);
  asm volatile("s_waitcnt vmcnt(4)" ::: "memory");   // A0,B0 landed; B1 (4 loads) may fly
  __builtin_amdgcn_s_barrier();

  for (int kt = 0; kt < 16; ++kt) {
    const int p = kt & 1;
    u16* Ap = &smem[p][0];
    u16* Bp = &smem[p][8192];
    u16* Aq = &smem[p ^ 1][0];
    const int kA = (kt + 1) * 64, kB = (kt + 2) * 64;
    bf16x8 b[4][2], a[2][2];
    // ---- phase A: full B frags + a rows 0..31 | stage A[kt+1] -> q ----
    #pragma unroll
    for (int j = 0; j < 4; ++j) {
      const int row = wc * 64 + j * 16 + ln;
      #pragma unroll
      for (int kk = 0; kk < 2; ++kk)
        b[j][kk] = ld8(Bp + row * 64 + (((kk * 4 + quad) ^ (row & 7)) << 3));
    }
    LOADA(0);
    if (kt < 15) stage_t(Aq, gA, kA);
    PHASE_PRE(); MFMAQ(0); PHASE_POST();
    // ---- phase B: a rows 32..63 | stage B[kt+2] -> p (B[kt] consumed in phase A) ----
    LOADA(1);
    if (kt < 14) stage_t(Bp, gB, kB);
    PHASE_PRE(); MFMAQ(1);
    __builtin_amdgcn_s_setprio(0);
    if (kt < 14) { asm volatile("s_waitcnt vmcnt(4)" ::: "memory"); }
    else         { asm volatile("s_waitcnt vmcnt(0)" ::: "memory"); }
    asm volatile("" ::: "memory");
    __builtin_amdgcn_s_barrier();
  }

  // ---- epilogue: LDS re-tile (32 KB in buf0) -> coalesced wide stores ----
  u16* Tl = &smem[0][0];
  const int which = n0 >> 10;                    // 0=Q 1=K 2=V, block-uniform
  const int b_ = m0 >> 11;                       // tile never crosses batch (2048%128==0)
  const int s0 = m0 & 2047;
  const int h0 = (n0 & 1023) >> 6;               // first of 2 heads in this block

  if (which < 2) {
    // --- E1: RoPE in regs, stage to row-major T[128 s][128 c], 16-chunk rotate swizzle ---
    // byte = sl*256 + (((c>>3) + 2*(sl&7)) & 15)*16 + (c&7)*2
    const float qs = which ? 1.0f : 0.18033688011112042f;  // log2(e)/8 on Q
    const float2* cs2 = (const float2*)cs;       // [s][64 d] (cos,sin)
    #pragma unroll
    for (int i = 0; i < 4; ++i) {
      const int slb = wr * 64 + i * 16 + quad * 4;
      #pragma unroll
      for (int j = 0; j < 4; ++j) {
        const int c = wc * 64 + j * 16 + ln;     // 0..127 block-local col
        const int d = c & 63;
        const float sgn = (d & 1) ? 1.0f : -1.0f;
        #pragma unroll
        for (int r = 0; r < 4; ++r) {
          const int sl = slb + r;
          const float v = acc[i][j][r];
          const float pp = __shfl_xor(v, 1);     // rotate-half partner (d^1)
          const float2 cv = cs2[(size_t)(s0 + sl) * 64 + d];
          const float val = (v * cv.x + sgn * pp * cv.y) * qs;
          *(u16*)((char*)Tl + sl * 256 + ((((c >> 3) + 2 * (sl & 7)) & 15) << 4)
                  + ((c & 7) << 1)) = f2b(val);
        }
      }
    }
    __syncthreads();
    // --- E2: wide stores; 2048 chunks over 8 iters; per instr 4 rows x 2x128B runs ---
    u16* dst = which ? Ko : Qo;
    #pragma unroll
    for (int it = 0; it < 8; ++it) {
      const int g = it * 256 + t;                // [sl(7)][ch(4)]
      const int ch = g & 15, sl = g >> 4;
      const int h = ch >> 3, c3 = ch & 7;
      const uint4 vv = *(const uint4*)((const char*)Tl + sl * 256
                        + (((ch + 2 * (sl & 7)) & 15) << 4));
      *(uint4*)(dst + ((size_t)(b_ * NH + h0 + h) * S_LEN + s0 + sl) * 64 + c3 * 8) = vv;
    }
  } else {
    // --- E1: stage to col-major T2[128 c][128 s]; r=0..3 s-contiguous -> uint2 writes ---
    // byte = c*256 + (((s>>3) + c) & 15)*16 + (s&7)*2   (s&7 in {0,4} -> aligned uint2)
    #pragma unroll
    for (int i = 0; i < 4; ++i) {
      const int slb = wr * 64 + i * 16 + quad * 4;
      #pragma unroll
      for (int j = 0; j < 4; ++j) {
        const int c = wc * 64 + j * 16 + ln;
        u16 pk[4];
        #pragma unroll
        for (int r = 0; r < 4; ++r) pk[r] = f2b(acc[i][j][r]);
        *(uint2*)((char*)Tl + c * 256 + ((((slb >> 3) + c) & 15) << 4)
                  + ((slb & 7) << 1)) = *(const uint2*)pk;
      }
    }
    __syncthreads();
    // --- E2: per instr 4 rows x 256B contiguous into Vt [bh][64][2048] ---
    #pragma unroll
    for (int it = 0; it < 8; ++it) {
      const int g = it * 256 + t;                // [cd(7)][sc(4)]
      const int sc = g & 15, cd = g >> 4;        // cd = block-local col 0..127
      const int h = cd >> 6, d = cd & 63;
      const uint4 vv = *(const uint4*)((const char*)Tl + cd * 256
                        + (((sc + cd) & 15) << 4));
      *(uint4*)(&Vt[((size_t)((b_ * NH + h0 + h) * 64 + d)) * S_LEN + s0 + sc * 8]) = vv;
    }
  }
}

#undef PHASE_PRE
#undef PHASE_POST
#undef LOADA
#undef MFMAQ

// ---------- flash attention, S^T/O^T formulation, QBLK=64 (r7-verbatim, validated) ----------
// Q,K: [bh][2048][64] (Q pre-scaled), Vt: [bh][64][2048]; Ao: [4096][1024] bf16
// r11 lesson: staging is the latency-hiding structure, not a BW filter — keep it.
__global__ __launch_bounds__(256) void attn_kernel(const u16* __restrict__ Qb,
                                                   const u16* __restrict__ Kb,
                                                   const u16* __restrict__ Vt,
                                                   u16* __restrict__ Ao) {
  __shared__ u16 smem[20480];          // Kl 2x4096 | Vl 2x4096 | Pl 4x1024 = 40960 B
  u16* Kl = smem;
  u16* Vl = smem + 8192;
  u16* Pl = smem + 16384;
  const int t = threadIdx.x;
  const int lane = t & 63, w = t >> 6;
  const int ln = lane & 15, quad = lane >> 4;
  // block decode: xcd-local bh (L2 reuse), per-CU-balanced qt
  const int i = blockIdx.x;
  const int xcd = i & 7;
  const int j = i >> 3;                  // 0..127
  const int bh = (xcd << 2) | (j & 3);   // 4 bh per XCD -> K/V L2-resident
  const int q5 = j >> 2;                 // 0..31
  const int g = q5 & 7, s5 = q5 >> 3;
  const int qt = (s5 & 1) ? (31 - ((s5 >> 1) << 3) - g) : (((s5 >> 1) << 3) + g);
  const int q0 = qt * 64;
  const int b = bh >> 4, h = bh & 15;
  const u16* Qbh = Qb + (size_t)bh * (S_LEN * 64);
  const u16* Kbh = Kb + (size_t)bh * (S_LEN * 64);
  const u16* Vtbh = Vt + (size_t)bh * (64 * S_LEN);
  u16* Plw = Pl + w * 1024;              // per-wave [16 q][64 t], 8-chunk XOR swizzled
  u16* AoBase = Ao + (size_t)b * S_LEN * DM + h * 64;

  auto stage = [&](int kt, int bufi) {
    u16* kd = Kl + bufi * 4096;
    u16* vd = Vl + bufi * 4096;
    const u16* kg = Kbh + (size_t)kt * 64 * 64;
    const u16* vg = Vtbh + (size_t)kt * 64;
    #pragma unroll
    for (int it = 0; it < 2; ++it) {
      int c = it * 256 + t;
      int row = c >> 3, sg = (c & 7) ^ (row & 7);
      glds16((const char*)kg + ((size_t)row * 64 + sg * 8) * 2,   (char*)kd + c * 16);
      glds16((const char*)vg + ((size_t)row * 2048 + sg * 8) * 2, (char*)vd + c * 16);
    }
  };

  // Q as B-fragment: n = this wave's 16 q rows
  bf16x8 bq[2];
  #pragma unroll
  for (int kk = 0; kk < 2; ++kk)
    bq[kk] = ld8(Qbh + (size_t)(q0 + w * 16 + ln) * 64 + kk * 32 + quad * 8);

  f32x4 o[4] = {};                       // O^T tiles: m=d (4 tiles), n=q
  float l = 0.f;                         // per-lane partial sum for q=ln over this quad's t

  stage(0, 0);
  __syncthreads();

  for (int kt = 0; kt <= qt; ++kt) {
    const int bufi = kt & 1;
    if (kt < qt) stage(kt + 1, bufi ^ 1);   // prefetch overlaps compute
    const u16* Kb_ = Kl + bufi * 4096;
    const u16* Vb_ = Vl + bufi * 4096;

    // S^T = K Q^T: A=K (m=t), B=Q (n=q)
    f32x4 st[4] = {};
    #pragma unroll
    for (int kk = 0; kk < 2; ++kk)
      #pragma unroll
      for (int ct = 0; ct < 4; ++ct) {
        bf16x8 ak = ld8(Kb_ + (ct * 16 + ln) * 64 + (((kk * 4 + quad) ^ (ln & 7)) << 3));
        st[ct] = mfma16(ak, bq[kk], st[ct]);
      }

    // exp2 + causal mask + l accumulate + P store (b64, swizzled)
    const bool diag = (kt == qt);
    #pragma unroll
    for (int ct = 0; ct < 4; ++ct) {
      u16 pk[4];
      #pragma unroll
      for (int r = 0; r < 4; ++r) {
        float p;
        if (diag && (ct * 16 + quad * 4 + r) > (w * 16 + ln)) p = 0.f;
        else p = __builtin_amdgcn_exp2f(st[ct][r]);
        l += p;
        pk[r] = f2b_trunc(p);
      }
      *(uint2*)(Plw + ln * 64 + ((((ct * 2) + (quad >> 1)) ^ (ln & 7)) << 3)
                + ((quad & 1) << 2)) = *(const uint2*)pk;
    }

    // O^T += Vt P^T: A=Vt (m=d), B=P (n=q)
    #pragma unroll
    for (int k4 = 0; k4 < 2; ++k4) {
      bf16x8 bp = ld8(Plw + ln * 64 + (((k4 * 4 + quad) ^ (ln & 7)) << 3));
      #pragma unroll
      for (int dt = 0; dt < 4; ++dt) {
        bf16x8 av = ld8(Vb_ + (dt * 16 + ln) * 64 + (((k4 * 4 + quad) ^ (ln & 7)) << 3));
        o[dt] = mfma16(av, bp, o[dt]);
      }
    }
    __syncthreads();                         // buf consumed; prefetch drained
  }

  // l: sum across the 4 quads holding q=ln
  l += __shfl_xor(l, 16);
  l += __shfl_xor(l, 32);
  const float inv = 1.f / l;
  const size_t qrow = (size_t)(q0 + w * 16 + ln) * DM;
  #pragma unroll
  for (int dt = 0; dt < 4; ++dt) {
    u16 pk[4];
    #pragma unroll
    for (int r = 0; r < 4; ++r) pk[r] = f2b(o[dt][r] * inv);
    *(uint2*)(AoBase + qrow + dt * 16 + quad * 4) = *(const uint2*)pk;
  }
}

// ---------- out-projection GEMM, TM x 128, BK=64, XOR-swizzled staging (r8, -3.3us) ----------
template <int TM>
__global__ __launch_bounds__(256) void gemm_out_t(const u16* __restrict__ A,
                                                  const u16* __restrict__ Bt,
                                                  void* __restrict__ Out,
                                                  const int* __restrict__ flag) {
  constexpr int MI = TM / 32;
  __shared__ u16 smem[(TM + 128) * 64];   // Al[TM][64] | Bl[128][64]
  u16* Al = smem;
  u16* Bl = smem + TM * 64;
  const int t = threadIdx.x;
  const int lane = t & 63, wave = t >> 6;
  const int ln = lane & 15, quad = lane >> 4;
  const int wr = wave >> 1, wc = wave & 1;
  const int m0 = blockIdx.x * TM, n0 = blockIdx.y * 128;
  const char* Ab = (const char*)A;
  const char* Bb = (const char*)Bt;
  f32x4 acc[MI][4] = {};

  for (int k0 = 0; k0 < 1024; k0 += 64) {
    __syncthreads();
    #pragma unroll
    for (int it = 0; it < TM / 32; ++it) {        // A: TM*8 chunks
      const int c = it * 256 + t;
      const int row = c >> 3, sg = (c & 7) ^ (row & 7);
      glds16(Ab + ((size_t)(m0 + row) * 1024 + k0 + sg * 8) * 2, (char*)Al + c * 16);
    }
    #pragma unroll
    for (int it = 0; it < 4; ++it) {              // B: 1024 chunks
      const int c = it * 256 + t;
      const int row = c >> 3, sg = (c & 7) ^ (row & 7);
      glds16(Bb + ((size_t)(n0 + row) * 1024 + k0 + sg * 8) * 2, (char*)Bl + c * 16);
    }
    __syncthreads();
    bf16x8 a[MI][2], b[4][2];
    #pragma unroll
    for (int i = 0; i < MI; ++i) {
      const int row = wr * (TM / 2) + i * 16 + ln;
      #pragma unroll
      for (int kk = 0; kk < 2; ++kk)
        a[i][kk] = ld8(Al + row * 64 + (((kk * 4 + quad) ^ (row & 7)) << 3));
    }
    #pragma unroll
    for (int j = 0; j < 4; ++j) {
      const int row = wc * 64 + j * 16 + ln;
      #pragma unroll
      for (int kk = 0; kk < 2; ++kk)
        b[j][kk] = ld8(Bl + row * 64 + (((kk * 4 + quad) ^ (row & 7)) << 3));
    }
    #pragma unroll
    for (int i = 0; i < MI; ++i)
      #pragma unroll
      for (int j = 0; j < 4; ++j) {
        acc[i][j] = mfma16(a[i][0], b[j][0], acc[i][j]);
        acc[i][j] = mfma16(a[i][1], b[j][1], acc[i][j]);
      }
  }

  const int fl = *flag;
  #pragma unroll
  for (int i = 0; i < MI; ++i)
    #pragma unroll
    for (int j = 0; j < 4; ++j)
      #pragma unroll
      for (int r = 0; r < 4; ++r) {
        int m = m0 + wr * (TM / 2) + i * 16 + quad * 4 + r;
        int c = n0 + wc * 64 + j * 16 + ln;
        float v = acc[i][j][r];
        if (fl) ((u16*)Out)[(size_t)m * DM + c] = f2b(v);
        else    ((float*)Out)[(size_t)m * DM + c] = v;
      }
}

// ---------- launch ----------
extern "C" void kernel_launch(void* const* d_in, const int* in_sizes, int n_in,
                              void* d_out, int out_size, void* d_ws, size_t ws_size,
                              hipStream_t stream) {
  (void)in_sizes; (void)n_in; (void)out_size; (void)ws_size;
  const void* x    = d_in[0];
  const void* wqkv = d_in[2];
  const void* wout = d_in[3];
  char* ws = (char*)d_ws;
  u16*  xb   = (u16*)(ws + 0);            // 8 MB [4096][1024]; Ao aliases after gemm_qkv
  u16*  Ao   = xb;
  u16*  wqT  = (u16*)(ws + 8388608);      // 6 MB [3072][1024]
  u16*  woT  = (u16*)(ws + 14680064);     // 2 MB [1024][1024]
  u16*  Qb   = (u16*)(ws + 16777216);     // 8 MB [32][2048][64]
  u16*  Kb   = (u16*)(ws + 25165824);     // 8 MB
  u16*  Vt   = (u16*)(ws + 33554432);     // 8 MB [32][64][2048]
  float* cs  = (float*)(ws + 41943040);   // 1 MB [2048 s][64 d] float2 (cos,sin)
  int*  flag = (int*)(ws + 42991616);

  prep_kernel<<<3584, 256, 0, stream>>>(x, wqkv, wout, xb, wqT, woT, cs, flag);
  gemm_qkv<<<dim3(32, 24), 256, 0, stream>>>(xb, wqT, Qb, Kb, Vt, cs);
  attn_kernel<<<1024, 256, 0, stream>>>(Qb, Kb, Vt, Ao);
  gemm_out_t<64><<<dim3(64, 8), 256, 0, stream>>>(Ao, woT, d_out, flag);
}

// Round 17
// 171.674 us; speedup vs baseline: 1.0291x; 1.0160x over previous
//
#include <hip/hip_runtime.h>
#include <stdint.h>

typedef unsigned short u16;
typedef __bf16 bf16x8 __attribute__((ext_vector_type(8)));
typedef float f32x4 __attribute__((ext_vector_type(4)));

#define S_LEN 2048
#define NH    16
#define DM    1024
#define N3    3072
#define MROWS 4096   // B*S

// ---------- scalar bf16 helpers ----------
__device__ __forceinline__ float b2f(u16 u) {
  unsigned int v = ((unsigned int)u) << 16;
  return __builtin_bit_cast(float, v);
}
__device__ __forceinline__ u16 f2b(float f) {
  unsigned int v = __builtin_bit_cast(unsigned int, f);
  v += 0x7fffu + ((v >> 16) & 1u);   // RNE
  return (u16)(v >> 16);
}
__device__ __forceinline__ u16 f2b_trunc(float f) {
  return (u16)(__builtin_bit_cast(unsigned int, f) >> 16);
}
__device__ __forceinline__ bf16x8 ld8(const u16* p) { return *(const bf16x8*)p; }
__device__ __forceinline__ f32x4 mfma16(bf16x8 a, bf16x8 b, f32x4 c) {
  return __builtin_amdgcn_mfma_f32_16x16x32_bf16(a, b, c, 0, 0, 0);
}
__device__ __forceinline__ void glds16(const void* g, void* l) {
  __builtin_amdgcn_global_load_lds(
      (const __attribute__((address_space(1))) unsigned int*)g,
      (__attribute__((address_space(3))) unsigned int*)l, 16, 0, 0);
}
// bf16-vs-f32 word test: low-16 as bf16, exponent in [100,134]
__device__ __forceinline__ int bfish(unsigned int w) {
  unsigned int e = (w >> 7) & 0xffu;
  return (e >= 100u && e <= 134u) ? 1 : 0;
}
// wave-sum (64 lanes) -> lane0; then one atomicAdd per wave
__device__ __forceinline__ void wave_cnt_add(int* cnt, int s, int lane) {
  s += __shfl_down(s, 32);
  s += __shfl_down(s, 16);
  s += __shfl_down(s, 8);
  s += __shfl_down(s, 4);
  s += __shfl_down(s, 2);
  s += __shfl_down(s, 1);
  if (lane == 0) atomicAdd(cnt, s);
}

// ---------- fused prep: x->bf16 + cs table + both weight transposes + flag ----------
// blocks [0,2048): x conv | [2048,2560): cs table | [2560,3328): wqkv^T | [3328,3584): wout^T
__global__ __launch_bounds__(256) void prep_kernel(const void* __restrict__ x,
                                                   const void* __restrict__ wqkv,
                                                   const void* __restrict__ wout,
                                                   u16* __restrict__ xb,
                                                   u16* __restrict__ wqT,
                                                   u16* __restrict__ woT,
                                                   float* __restrict__ cs,
                                                   int* __restrict__ flag) {
  const int bx = blockIdx.x;
  const int t = threadIdx.x;
  if (bx < 2048) {                       // x -> bf16, self-detecting
    __shared__ int cnt;
    if (t == 0) cnt = 0;
    __syncthreads();
    size_t i = (size_t)bx * 256 + t;     // 524288 uint4 slots (safe both dtypes)
    const uint4* xv = (const uint4*)x;
    uint4 probe = xv[i];
    unsigned int wds[4]; *(uint4*)wds = probe;
    wave_cnt_add(&cnt, bfish(wds[0]) + bfish(wds[1]) + bfish(wds[2]) + bfish(wds[3]),
                 t & 63);
    __syncthreads();
    const int isbf = cnt > 512;
    if (t == 0) *flag = isbf;            // benign same-value race
    if (isbf) {
      ((uint4*)xb)[i] = probe;
    } else {
      // fp32 path, coalesced: 2x float4 loads (16B/lane contiguous) + uint2 stores
      const float4* xf4 = (const float4*)x;
      uint2* xb2 = (uint2*)xb;
      #pragma unroll
      for (int half = 0; half < 2; ++half) {
        const size_t idx = (size_t)bx * 512 + half * 256 + t;
        const float4 v = xf4[idx];
        u16 pk[4];
        pk[0] = f2b(v.x); pk[1] = f2b(v.y); pk[2] = f2b(v.z); pk[3] = f2b(v.w);
        xb2[idx] = *(const uint2*)pk;
      }
    }
    return;
  }
  if (bx < 2560) {                       // cs table: [2048 s][64 d] float2 (cos,sin)
    int i = (bx - 2048) * 256 + t;       // 131072 = 2048*64
    int s = i >> 6, d = i & 63;          // s-major -> coalesced float2 stores
    int f = d & 31;                      // concat(freqs,freqs): inv_freq index = d mod 32
    float invf = expf(-(float)(2 * f) * (1.0f / 64.0f) * logf(10000.0f));
    float th = (float)s * invf;
    float sv, cv;
    sincosf(th, &sv, &cv);
    cs[i * 2] = cv; cs[i * 2 + 1] = sv;  // i*2 == (s*64+d)*2
    return;
  }
  // weight transpose [R=1024][C] -> bf16 [C][1024], 64x64 tiles (V-transpose pattern)
  const int wq = bx < 3328;
  const int id = wq ? (bx - 2560) : (bx - 3328);
  const int ncx = wq ? 48 : 16;
  const void* in = wq ? wqkv : wout;
  u16* out = wq ? wqT : woT;
  const int C = wq ? 3072 : 1024;
  const int c0 = (id % ncx) * 64, r0 = (id / ncx) * 64;
  __shared__ int cnt;
  __shared__ u16 L[4096];                // [64 c][64 r], r-seg XOR swizzled
  if (t == 0) cnt = 0;
  __syncthreads();
  const unsigned int* wv = (const unsigned int*)in;
  size_t off = (((size_t)id) * 256 + t) & 262143;   // sample first 256K words (safe both)
  wave_cnt_add(&cnt, bfish(wv[off]), t & 63);
  __syncthreads();
  const int fl = cnt > 128;
  if (fl) {                              // bf16: uint4 loads, unpack into swizzled LDS
    #pragma unroll
    for (int it = 0; it < 2; ++it) {
      int c = it * 256 + t;
      int rl = c >> 3, cseg = c & 7;
      uint4 v = *(const uint4*)((const u16*)in + (size_t)(r0 + rl) * C + c0 + cseg * 8);
      u16 e[8]; *(uint4*)e = v;
      #pragma unroll
      for (int jj = 0; jj < 8; ++jj) {
        int cl = cseg * 8 + jj;
        L[cl * 64 + (rl ^ (cseg << 3))] = e[jj];
      }
    }
  } else {                               // fp32 fallback: scalar convert (already coalesced)
    const float* inf_ = (const float*)in;
    #pragma unroll
    for (int it = 0; it < 16; ++it) {
      int c = it * 256 + t;
      int rl = c >> 6, cl = c & 63;
      L[cl * 64 + (rl ^ ((cl >> 3) << 3))] = f2b(inf_[(size_t)(r0 + rl) * C + c0 + cl]);
    }
  }
  __syncthreads();
  #pragma unroll
  for (int it = 0; it < 2; ++it) {
    int c = it * 256 + t;
    int cl = c >> 3, rseg = c & 7;
    uint4 v = *(const uint4*)(L + cl * 64 + (((rseg ^ (cl >> 3)) & 7) << 3));
    *(uint4*)(out + (size_t)(c0 + cl) * 1024 + r0 + rseg * 8) = v;
  }
}

// ---------- QKV GEMM: 128x128 tile, BK=64, 4-wave merged-2-phase counted-vmcnt ----------
// (r16-verbatim, validated 174.4us: 2 blocks/CU, grid 768, full staging, vmcnt(4))
#define PHASE_PRE() do { \
  asm volatile("" ::: "memory"); \
  __builtin_amdgcn_s_barrier(); \
  asm volatile("s_waitcnt lgkmcnt(0)" ::: "memory"); \
  __builtin_amdgcn_sched_barrier(0); \
  __builtin_amdgcn_s_setprio(1); \
} while (0)

#define PHASE_POST() do { \
  __builtin_amdgcn_s_setprio(0); \
  asm volatile("" ::: "memory"); \
  __builtin_amdgcn_s_barrier(); \
} while (0)

#define LOADA(P) \
  _Pragma("unroll") \
  for (int ii = 0; ii < 2; ++ii) { \
    const int row = wr * 64 + ((P) * 2 + ii) * 16 + ln; \
    _Pragma("unroll") \
    for (int kk = 0; kk < 2; ++kk) \
      a[ii][kk] = ld8(Ap + row * 64 + (((kk * 4 + quad) ^ (row & 7)) << 3)); \
  }

#define MFMAQ(P) \
  _Pragma("unroll") \
  for (int ii = 0; ii < 2; ++ii) { \
    _Pragma("unroll") \
    for (int j = 0; j < 4; ++j) { \
      acc[(P) * 2 + ii][j] = mfma16(a[ii][0], b[j][0], acc[(P) * 2 + ii][j]); \
      acc[(P) * 2 + ii][j] = mfma16(a[ii][1], b[j][1], acc[(P) * 2 + ii][j]); \
    } \
  }

__global__ __launch_bounds__(256) void gemm_qkv(const u16* __restrict__ A,
                                                const u16* __restrict__ Bt,
                                                u16* __restrict__ Qo,
                                                u16* __restrict__ Ko,
                                                u16* __restrict__ Vt,
                                                const float* __restrict__ cs) {
  __shared__ u16 smem[2][16384];        // per buf: A[128][64] | B[128][64] = 32 KB; 64 KB total
  const int t = threadIdx.x;
  const int lane = t & 63, wave = t >> 6;
  const int ln = lane & 15, quad = lane >> 4;
  const int wr = wave >> 1, wc = wave & 1;        // 2M x 2N waves; per-wave C = 64x64
  const int m0 = blockIdx.x * 128, n0 = blockIdx.y * 128;
  const u16* gA = A + (size_t)m0 * 1024;
  const u16* gB = Bt + (size_t)n0 * 1024;
  f32x4 acc[4][4] = {};

  // stage one 128x64 tile: 1024 chunks of 16B, 4 glds/thread; inverse-swz source.
  auto stage_t = [&](u16* lds, const u16* g, int k0) {
    #pragma unroll
    for (int it = 0; it < 4; ++it) {
      const int c = it * 256 + t;
      const int row = c >> 3, sg = (c & 7) ^ (row & 7);
      glds16(g + (size_t)row * 1024 + k0 + sg * 8, (char*)lds + c * 16);
    }
  };

  // prologue: A[0],B[0] -> buf0; B[1] -> buf1 (A[1] staged during kt=0)
  stage_t(&smem[0][0],    gA, 0);
  stage_t(&smem[0][8192], gB, 0);
  stage_t(&smem[1][8192], gB, 64);
  asm volatile("s_waitcnt vmcnt(4)" ::: "memory");   // A0,B0 landed; B1 (4 loads) may fly
  __builtin_amdgcn_s_barrier();

  for (int kt = 0; kt < 16; ++kt) {
    const int p = kt & 1;
    u16* Ap = &smem[p][0];
    u16* Bp = &smem[p][8192];
    u16* Aq = &smem[p ^ 1][0];
    const int kA = (kt + 1) * 64, kB = (kt + 2) * 64;
    bf16x8 b[4][2], a[2][2];
    // ---- phase A: full B frags + a rows 0..31 | stage A[kt+1] -> q ----
    #pragma unroll
    for (int j = 0; j < 4; ++j) {
      const int row = wc * 64 + j * 16 + ln;
      #pragma unroll
      for (int kk = 0; kk < 2; ++kk)
        b[j][kk] = ld8(Bp + row * 64 + (((kk * 4 + quad) ^ (row & 7)) << 3));
    }
    LOADA(0);
    if (kt < 15) stage_t(Aq, gA, kA);
    PHASE_PRE(); MFMAQ(0); PHASE_POST();
    // ---- phase B: a rows 32..63 | stage B[kt+2] -> p (B[kt] consumed in phase A) ----
    LOADA(1);
    if (kt < 14) stage_t(Bp, gB, kB);
    PHASE_PRE(); MFMAQ(1);
    __builtin_amdgcn_s_setprio(0);
    if (kt < 14) { asm volatile("s_waitcnt vmcnt(4)" ::: "memory"); }
    else         { asm volatile("s_waitcnt vmcnt(0)" ::: "memory"); }
    asm volatile("" ::: "memory");
    __builtin_amdgcn_s_barrier();
  }

  // ---- epilogue: LDS re-tile (32 KB in buf0) -> coalesced wide stores ----
  u16* Tl = &smem[0][0];
  const int which = n0 >> 10;                    // 0=Q 1=K 2=V, block-uniform
  const int b_ = m0 >> 11;                       // tile never crosses batch (2048%128==0)
  const int s0 = m0 & 2047;
  const int h0 = (n0 & 1023) >> 6;               // first of 2 heads in this block

  if (which < 2) {
    // --- E1: RoPE in regs, stage to row-major T[128 s][128 c], 16-chunk rotate swizzle ---
    // byte = sl*256 + (((c>>3) + 2*(sl&7)) & 15)*16 + (c&7)*2
    const float qs = which ? 1.0f : 0.18033688011112042f;  // log2(e)/8 on Q
    const float2* cs2 = (const float2*)cs;       // [s][64 d] (cos,sin)
    #pragma unroll
    for (int i = 0; i < 4; ++i) {
      const int slb = wr * 64 + i * 16 + quad * 4;
      #pragma unroll
      for (int j = 0; j < 4; ++j) {
        const int c = wc * 64 + j * 16 + ln;     // 0..127 block-local col
        const int d = c & 63;
        const float sgn = (d & 1) ? 1.0f : -1.0f;
        #pragma unroll
        for (int r = 0; r < 4; ++r) {
          const int sl = slb + r;
          const float v = acc[i][j][r];
          const float pp = __shfl_xor(v, 1);     // rotate-half partner (d^1)
          const float2 cv = cs2[(size_t)(s0 + sl) * 64 + d];
          const float val = (v * cv.x + sgn * pp * cv.y) * qs;
          *(u16*)((char*)Tl + sl * 256 + ((((c >> 3) + 2 * (sl & 7)) & 15) << 4)
                  + ((c & 7) << 1)) = f2b(val);
        }
      }
    }
    __syncthreads();
    // --- E2: wide stores; 2048 chunks over 8 iters; per instr 4 rows x 2x128B runs ---
    u16* dst = which ? Ko : Qo;
    #pragma unroll
    for (int it = 0; it < 8; ++it) {
      const int g = it * 256 + t;                // [sl(7)][ch(4)]
      const int ch = g & 15, sl = g >> 4;
      const int h = ch >> 3, c3 = ch & 7;
      const uint4 vv = *(const uint4*)((const char*)Tl + sl * 256
                        + (((ch + 2 * (sl & 7)) & 15) << 4));
      *(uint4*)(dst + ((size_t)(b_ * NH + h0 + h) * S_LEN + s0 + sl) * 64 + c3 * 8) = vv;
    }
  } else {
    // --- E1: stage to col-major T2[128 c][128 s]; r=0..3 s-contiguous -> uint2 writes ---
    // byte = c*256 + (((s>>3) + c) & 15)*16 + (s&7)*2   (s&7 in {0,4} -> aligned uint2)
    #pragma unroll
    for (int i = 0; i < 4; ++i) {
      const int slb = wr * 64 + i * 16 + quad * 4;
      #pragma unroll
      for (int j = 0; j < 4; ++j) {
        const int c = wc * 64 + j * 16 + ln;
        u16 pk[4];
        #pragma unroll
        for (int r = 0; r < 4; ++r) pk[r] = f2b(acc[i][j][r]);
        *(uint2*)((char*)Tl + c * 256 + ((((slb >> 3) + c) & 15) << 4)
                  + ((slb & 7) << 1)) = *(const uint2*)pk;
      }
    }
    __syncthreads();
    // --- E2: per instr 4 rows x 256B contiguous into Vt [bh][64][2048] ---
    #pragma unroll
    for (int it = 0; it < 8; ++it) {
      const int g = it * 256 + t;                // [cd(7)][sc(4)]
      const int sc = g & 15, cd = g >> 4;        // cd = block-local col 0..127
      const int h = cd >> 6, d = cd & 63;
      const uint4 vv = *(const uint4*)((const char*)Tl + cd * 256
                        + (((sc + cd) & 15) << 4));
      *(uint4*)(&Vt[((size_t)((b_ * NH + h0 + h) * 64 + d)) * S_LEN + s0 + sc * 8]) = vv;
    }
  }
}

// ---------- flash attention, S^T/O^T formulation, QBLK=64 (r7-verbatim, validated) ----------
// Q,K: [bh][2048][64] (Q pre-scaled), Vt: [bh][64][2048]; Ao: [4096][1024] bf16
// r11 lesson: staging is the latency-hiding structure, not a BW filter — keep it.
__global__ __launch_bounds__(256) void attn_kernel(const u16* __restrict__ Qb,
                                                   const u16* __restrict__ Kb,
                                                   const u16* __restrict__ Vt,
                                                   u16* __restrict__ Ao) {
  __shared__ u16 smem[20480];          // Kl 2x4096 | Vl 2x4096 | Pl 4x1024 = 40960 B
  u16* Kl = smem;
  u16* Vl = smem + 8192;
  u16* Pl = smem + 16384;
  const int t = threadIdx.x;
  const int lane = t & 63, w = t >> 6;
  const int ln = lane & 15, quad = lane >> 4;
  // block decode: xcd-local bh (L2 reuse), per-CU-balanced qt
  const int i = blockIdx.x;
  const int xcd = i & 7;
  const int j = i >> 3;                  // 0..127
  const int bh = (xcd << 2) | (j & 3);   // 4 bh per XCD -> K/V L2-resident
  const int q5 = j >> 2;                 // 0..31
  const int g = q5 & 7, s5 = q5 >> 3;
  const int qt = (s5 & 1) ? (31 - ((s5 >> 1) << 3) - g) : (((s5 >> 1) << 3) + g);
  const int q0 = qt * 64;
  const int b = bh >> 4, h = bh & 15;
  const u16* Qbh = Qb + (size_t)bh * (S_LEN * 64);
  const u16* Kbh = Kb + (size_t)bh * (S_LEN * 64);
  const u16* Vtbh = Vt + (size_t)bh * (64 * S_LEN);
  u16* Plw = Pl + w * 1024;              // per-wave [16 q][64 t], 8-chunk XOR swizzled
  u16* AoBase = Ao + (size_t)b * S_LEN * DM + h * 64;

  auto stage = [&](int kt, int bufi) {
    u16* kd = Kl + bufi * 4096;
    u16* vd = Vl + bufi * 4096;
    const u16* kg = Kbh + (size_t)kt * 64 * 64;
    const u16* vg = Vtbh + (size_t)kt * 64;
    #pragma unroll
    for (int it = 0; it < 2; ++it) {
      int c = it * 256 + t;
      int row = c >> 3, sg = (c & 7) ^ (row & 7);
      glds16((const char*)kg + ((size_t)row * 64 + sg * 8) * 2,   (char*)kd + c * 16);
      glds16((const char*)vg + ((size_t)row * 2048 + sg * 8) * 2, (char*)vd + c * 16);
    }
  };

  // Q as B-fragment: n = this wave's 16 q rows
  bf16x8 bq[2];
  #pragma unroll
  for (int kk = 0; kk < 2; ++kk)
    bq[kk] = ld8(Qbh + (size_t)(q0 + w * 16 + ln) * 64 + kk * 32 + quad * 8);

  f32x4 o[4] = {};                       // O^T tiles: m=d (4 tiles), n=q
  float l = 0.f;                         // per-lane partial sum for q=ln over this quad's t

  stage(0, 0);
  __syncthreads();

  for (int kt = 0; kt <= qt; ++kt) {
    const int bufi = kt & 1;
    if (kt < qt) stage(kt + 1, bufi ^ 1);   // prefetch overlaps compute
    const u16* Kb_ = Kl + bufi * 4096;
    const u16* Vb_ = Vl + bufi * 4096;

    // S^T = K Q^T: A=K (m=t), B=Q (n=q)
    f32x4 st[4] = {};
    #pragma unroll
    for (int kk = 0; kk < 2; ++kk)
      #pragma unroll
      for (int ct = 0; ct < 4; ++ct) {
        bf16x8 ak = ld8(Kb_ + (ct * 16 + ln) * 64 + (((kk * 4 + quad) ^ (ln & 7)) << 3));
        st[ct] = mfma16(ak, bq[kk], st[ct]);
      }

    // exp2 + causal mask + l accumulate + P store (b64, swizzled)
    const bool diag = (kt == qt);
    #pragma unroll
    for (int ct = 0; ct < 4; ++ct) {
      u16 pk[4];
      #pragma unroll
      for (int r = 0; r < 4; ++r) {
        float p;
        if (diag && (ct * 16 + quad * 4 + r) > (w * 16 + ln)) p = 0.f;
        else p = __builtin_amdgcn_exp2f(st[ct][r]);
        l += p;
        pk[r] = f2b_trunc(p);
      }
      *(uint2*)(Plw + ln * 64 + ((((ct * 2) + (quad >> 1)) ^ (ln & 7)) << 3)
                + ((quad & 1) << 2)) = *(const uint2*)pk;
    }

    // O^T += Vt P^T: A=Vt (m=d), B=P (n=q)
    #pragma unroll
    for (int k4 = 0; k4 < 2; ++k4) {
      bf16x8 bp = ld8(Plw + ln * 64 + (((k4 * 4 + quad) ^ (ln & 7)) << 3));
      #pragma unroll
      for (int dt = 0; dt < 4; ++dt) {
        bf16x8 av = ld8(Vb_ + (dt * 16 + ln) * 64 + (((k4 * 4 + quad) ^ (ln & 7)) << 3));
        o[dt] = mfma16(av, bp, o[dt]);
      }
    }
    __syncthreads();                         // buf consumed; prefetch drained
  }

  // l: sum across the 4 quads holding q=ln
  l += __shfl_xor(l, 16);
  l += __shfl_xor(l, 32);
  const float inv = 1.f / l;
  const size_t qrow = (size_t)(q0 + w * 16 + ln) * DM;
  #pragma unroll
  for (int dt = 0; dt < 4; ++dt) {
    u16 pk[4];
    #pragma unroll
    for (int r = 0; r < 4; ++r) pk[r] = f2b(o[dt][r] * inv);
    *(uint2*)(AoBase + qrow + dt * 16 + quad * 4) = *(const uint2*)pk;
  }
}

// ---------- out-projection GEMM: 64x128, BK=64, 4-wave 2-phase counted-vmcnt ----------
// r17: port of the (twice-validated) counted-vmcnt double-buffer to gemm_out.
// Staging audit: A-tile 64x64 bf16 = 8 KB = 512 chunks = 2 it x 256 thr (2 glds/thr);
// B-tile 128x64 = 16 KB = 1024 chunks = 4 it (4 glds/thr). LDS 2x24 KB = 48 KB.
// vmcnt: checkpoint leaves only B[kt+2]'s 4 in flight -> vmcnt(4); kt>=14 drain 0.
__global__ __launch_bounds__(256) void gemm_out(const u16* __restrict__ A,
                                                const u16* __restrict__ Bt,
                                                void* __restrict__ Out,
                                                const int* __restrict__ flag) {
  __shared__ u16 smem[2][12288];        // per buf: Al[64][64] (4096) | Bl[128][64] (8192)
  const int t = threadIdx.x;
  const int lane = t & 63, wave = t >> 6;
  const int ln = lane & 15, quad = lane >> 4;
  const int wr = wave >> 1, wc = wave & 1;        // per-wave C = 32x64
  const int m0 = blockIdx.x * 64, n0 = blockIdx.y * 128;
  const u16* gA = A + (size_t)m0 * 1024;
  const u16* gB = Bt + (size_t)n0 * 1024;
  f32x4 acc[2][4] = {};

  auto stage_A = [&](u16* lds, int k0) {          // 512 chunks, 2 glds/thread
    #pragma unroll
    for (int it = 0; it < 2; ++it) {
      const int c = it * 256 + t;
      const int row = c >> 3, sg = (c & 7) ^ (row & 7);
      glds16(gA + (size_t)row * 1024 + k0 + sg * 8, (char*)lds + c * 16);
    }
  };
  auto stage_B = [&](u16* lds, int k0) {          // 1024 chunks, 4 glds/thread
    #pragma unroll
    for (int it = 0; it < 4; ++it) {
      const int c = it * 256 + t;
      const int row = c >> 3, sg = (c & 7) ^ (row & 7);
      glds16(gB + (size_t)row * 1024 + k0 + sg * 8, (char*)lds + c * 16);
    }
  };

  // prologue: A[0],B[0] -> buf0; B[1] -> buf1 (A[1] staged during kt=0)
  stage_A(&smem[0][0], 0);
  stage_B(&smem[0][4096], 0);
  stage_B(&smem[1][4096], 64);
  asm volatile("s_waitcnt vmcnt(4)" ::: "memory");   // A0,B0 landed; B1 may fly
  __builtin_amdgcn_s_barrier();

  for (int kt = 0; kt < 16; ++kt) {
    const int p = kt & 1;
    u16* Ap = &smem[p][0];
    u16* Bp = &smem[p][4096];
    u16* Aq = &smem[p ^ 1][0];
    const int kA = (kt + 1) * 64, kB = (kt + 2) * 64;
    bf16x8 b[4][2], a[2][2];
    // ---- phase A: full B frags + a[0] | stage A[kt+1] -> q ----
    #pragma unroll
    for (int j = 0; j < 4; ++j) {
      const int row = wc * 64 + j * 16 + ln;
      #pragma unroll
      for (int kk = 0; kk < 2; ++kk)
        b[j][kk] = ld8(Bp + row * 64 + (((kk * 4 + quad) ^ (row & 7)) << 3));
    }
    {
      const int row = wr * 32 + ln;
      #pragma unroll
      for (int kk = 0; kk < 2; ++kk)
        a[0][kk] = ld8(Ap + row * 64 + (((kk * 4 + quad) ^ (row & 7)) << 3));
    }
    if (kt < 15) stage_A(Aq, kA);
    PHASE_PRE();
    #pragma unroll
    for (int j = 0; j < 4; ++j) {
      acc[0][j] = mfma16(a[0][0], b[j][0], acc[0][j]);
      acc[0][j] = mfma16(a[0][1], b[j][1], acc[0][j]);
    }
    PHASE_POST();
    // ---- phase B: a[1] | stage B[kt+2] -> p (B[kt] consumed in phase A) ----
    {
      const int row = wr * 32 + 16 + ln;
      #pragma unroll
      for (int kk = 0; kk < 2; ++kk)
        a[1][kk] = ld8(Ap + row * 64 + (((kk * 4 + quad) ^ (row & 7)) << 3));
    }
    if (kt < 14) stage_B(Bp, kB);
    PHASE_PRE();
    #pragma unroll
    for (int j = 0; j < 4; ++j) {
      acc[1][j] = mfma16(a[1][0], b[j][0], acc[1][j]);
      acc[1][j] = mfma16(a[1][1], b[j][1], acc[1][j]);
    }
    __builtin_amdgcn_s_setprio(0);
    if (kt < 14) { asm volatile("s_waitcnt vmcnt(4)" ::: "memory"); }
    else         { asm volatile("s_waitcnt vmcnt(0)" ::: "memory"); }
    asm volatile("" ::: "memory");
    __builtin_amdgcn_s_barrier();
  }

  const int fl = *flag;
  #pragma unroll
  for (int i = 0; i < 2; ++i)
    #pragma unroll
    for (int j = 0; j < 4; ++j)
      #pragma unroll
      for (int r = 0; r < 4; ++r) {
        int m = m0 + wr * 32 + i * 16 + quad * 4 + r;
        int c = n0 + wc * 64 + j * 16 + ln;
        float v = acc[i][j][r];
        if (fl) ((u16*)Out)[(size_t)m * DM + c] = f2b(v);
        else    ((float*)Out)[(size_t)m * DM + c] = v;
      }
}

#undef PHASE_PRE
#undef PHASE_POST
#undef LOADA
#undef MFMAQ

// ---------- launch ----------
extern "C" void kernel_launch(void* const* d_in, const int* in_sizes, int n_in,
                              void* d_out, int out_size, void* d_ws, size_t ws_size,
                              hipStream_t stream) {
  (void)in_sizes; (void)n_in; (void)out_size; (void)ws_size;
  const void* x    = d_in[0];
  const void* wqkv = d_in[2];
  const void* wout = d_in[3];
  char* ws = (char*)d_ws;
  u16*  xb   = (u16*)(ws + 0);            // 8 MB [4096][1024]; Ao aliases after gemm_qkv
  u16*  Ao   = xb;
  u16*  wqT  = (u16*)(ws + 8388608);      // 6 MB [3072][1024]
  u16*  woT  = (u16*)(ws + 14680064);     // 2 MB [1024][1024]
  u16*  Qb   = (u16*)(ws + 16777216);     // 8 MB [32][2048][64]
  u16*  Kb   = (u16*)(ws + 25165824);     // 8 MB
  u16*  Vt   = (u16*)(ws + 33554432);     // 8 MB [32][64][2048]
  float* cs  = (float*)(ws + 41943040);   // 1 MB [2048 s][64 d] float2 (cos,sin)
  int*  flag = (int*)(ws + 42991616);

  prep_kernel<<<3584, 256, 0, stream>>>(x, wqkv, wout, xb, wqT, woT, cs, flag);
  gemm_qkv<<<dim3(32, 24), 256, 0, stream>>>(xb, wqT, Qb, Kb, Vt, cs);
  attn_kernel<<<1024, 256, 0, stream>>>(Qb, Kb, Vt, Ao);
  gemm_out<<<dim3(64, 8), 256, 0, stream>>>(Ao, woT, d_out, flag);
}